// Round 17
// baseline (205.312 us; speedup 1.0000x reference)
//
#include <hip/hip_runtime.h>
#include <hip/hip_bf16.h>

// B=64, T=2048, D=784, N1=100, N2=10, dt=0.04
// Pipeline:
//   prep_w16 : W1 -> fp16 2-way split (h, r*1024) in FRAGMENT ORDER (r16 verbatim)
//   gemm1_x  : z1 = batch @ W1^T, 3-term fp16 split, barrier-free K-loop (r16
//              structure) at HIGH OCCUPANCY: rt=1 (acc 56 VGPR), launch_bounds
//              (512,4) -> 4 waves/SIMD; W persistent in LDS in 5-tile sections
//              (71680 B -> 2 blocks/CU = 16 waves/CU). BM=128, grid 1024.
//   fused_scan3: scan1 + gemm2 + scan2 (round-15/16 version verbatim).
//
// ws: Wg 358400 B | z1p 131072*100 f32 (52.4 MB)

#define FHN_DT 0.04f

typedef _Float16 f16x8 __attribute__((ext_vector_type(8)));
typedef __attribute__((ext_vector_type(4))) float f32x4;

__device__ __forceinline__ void gl16(const void* g, void* l) {
    __builtin_amdgcn_global_load_lds(
        (const __attribute__((address_space(1))) unsigned int*)g,
        (__attribute__((address_space(3))) unsigned int*)l, 16, 0, 0);
}

__device__ __forceinline__ void sync_lds() {
    asm volatile("s_waitcnt lgkmcnt(0)" ::: "memory");
    __builtin_amdgcn_s_barrier();
    asm volatile("" ::: "memory");
}

// ---------------- prep: W1 (100x784) -> fragment-order fp16 split image (r16 verbatim) ----------------
__global__ void prep_w16(const float* __restrict__ W1, unsigned short* __restrict__ Wg) {
    int idx = blockIdx.x * 256 + threadIdx.x;
    if (idx >= 179200) return;
    int kt   = idx / 7168;
    int rem  = idx % 7168;
    int f    = rem >> 9;
    int r2   = rem & 511;
    int l    = r2 >> 3;
    int e    = r2 & 7;
    int term = f / 7, ct = f % 7;
    int n = ct * 16 + (l & 15);
    int k = kt * 32 + (l >> 4) * 8 + e;
    float v = (n < 100 && k < 784) ? W1[n * 784 + k] : 0.0f;
    _Float16 h = (_Float16)v;
    unsigned short o;
    if (term == 0) o = __builtin_bit_cast(unsigned short, h);
    else           o = __builtin_bit_cast(unsigned short, (_Float16)((v - (float)h) * 1024.0f));
    Wg[idx] = o;
}

// ---------------- GEMM1: barrier-free, rt=1, 4 waves/SIMD, W in 5-tile LDS sections ----------------
__global__ __launch_bounds__(512, 4) void gemm1_x(const float* __restrict__ A,
                                                  const unsigned short* __restrict__ Wg,
                                                  float* __restrict__ z1p) {
    __shared__ __align__(16) char smem[71680];     // 5 tiles x 14336 B
    const int tid  = threadIdx.x;                  // 0..511
    const int w    = tid >> 6;                     // 0..7
    const int lane = tid & 63;
    const int ln   = lane & 15;
    const int kg   = lane >> 4;                    // k-slice = kg*8
    const long row0 = (long)blockIdx.x * 128;

    const float* arow = A + (row0 + w * 16 + ln) * 784 + kg * 8;

    f32x4 acc1[7] = {};
    f32x4 acc2[7] = {};
    float afpA[8], afpB[8];

#define ISSUE_A(T, AF) {                                                        \
        if ((T) == 24 && kg >= 2) {                                             \
            *(float4*)&AF[0] = make_float4(0.f, 0.f, 0.f, 0.f);                 \
            *(float4*)&AF[4] = make_float4(0.f, 0.f, 0.f, 0.f);                 \
        } else {                                                                \
            *(float4*)&AF[0] = *(const float4*)(arow + (T) * 32);               \
            *(float4*)&AF[4] = *(const float4*)(arow + (T) * 32 + 4);           \
        } }

    // bulk 5-tile section copy: 71680 B = 8 x 8192 + 6144 tail
#define LOADSEC(TS) {                                                           \
        const char* src_ = (const char*)Wg + (size_t)(TS) * 14336;              \
        _Pragma("unroll 1")                                                     \
        for (int c_ = 0; c_ < 8; ++c_)                                          \
            gl16(src_ + c_ * 8192 + tid * 16, smem + c_ * 8192 + tid * 16);     \
        if (tid < 384)                                                          \
            gl16(src_ + 65536 + tid * 16, smem + 65536 + tid * 16);             \
    }

#define SEC_SYNC() {                                                            \
        asm volatile("s_waitcnt vmcnt(0)" ::: "memory");                        \
        __builtin_amdgcn_s_barrier();                                           \
        asm volatile("" ::: "memory");                                          \
    }

#define BODY(KT, AF, TS) {                                                      \
        f16x8 ah, al;                                                           \
        _Pragma("unroll")                                                       \
        for (int e_ = 0; e_ < 8; ++e_) {                                        \
            float a_ = AF[e_];                                                  \
            _Float16 h_ = (_Float16)a_;                                         \
            ah[e_] = h_;                                                        \
            al[e_] = (_Float16)((a_ - (float)h_) * 1024.0f);                    \
        }                                                                       \
        if ((KT) < 23) ISSUE_A((KT) + 2, AF);                                   \
        const char* cb_ = smem + ((KT) - (TS)) * 14336 + lane * 16;             \
        _Pragma("unroll")                                                       \
        for (int ct_ = 0; ct_ < 7; ++ct_) {                                     \
            f16x8 bh = *(const f16x8*)(cb_ + ct_ * 1024);                       \
            f16x8 bl = *(const f16x8*)(cb_ + 7168 + ct_ * 1024);                \
            acc1[ct_] = __builtin_amdgcn_mfma_f32_16x16x32_f16(ah, bh, acc1[ct_], 0, 0, 0); \
            acc2[ct_] = __builtin_amdgcn_mfma_f32_16x16x32_f16(ah, bl, acc2[ct_], 0, 0, 0); \
            acc2[ct_] = __builtin_amdgcn_mfma_f32_16x16x32_f16(al, bh, acc2[ct_], 0, 0, 0); \
        } }

    // section = [pre-barrier] + DMA + vmcnt0-barrier + 5 barrier-free bodies
#define SECTION(TS, F0, F1) {                                                   \
        if ((TS) > 0) {                                                         \
            asm volatile("" ::: "memory");                                      \
            __builtin_amdgcn_s_barrier();   /* all waves done reading prev */   \
            asm volatile("" ::: "memory");                                      \
        }                                                                       \
        LOADSEC(TS);                                                            \
        SEC_SYNC();                                                             \
        BODY((TS) + 0, F0, TS);                                                 \
        BODY((TS) + 1, F1, TS);                                                 \
        BODY((TS) + 2, F0, TS);                                                 \
        BODY((TS) + 3, F1, TS);                                                 \
        BODY((TS) + 4, F0, TS);                                                 \
    }

    // prologue: A tiles 0,1 in flight
    ISSUE_A(0, afpA);
    ISSUE_A(1, afpB);

    SECTION(0,  afpA, afpB);
    SECTION(5,  afpB, afpA);
    SECTION(10, afpA, afpB);
    SECTION(15, afpB, afpA);
    SECTION(20, afpA, afpB);

    // ---- epilogue: C/D map col = lane&15, row = kg*4 + r ; z = acc1 + acc2/1024 ----
#pragma unroll
    for (int ct = 0; ct < 7; ++ct) {
        int n = ct * 16 + ln;
        if (n < 100) {
            float* p = z1p + (row0 + w * 16 + kg * 4) * 100 + n;
#pragma unroll
            for (int r = 0; r < 4; ++r)
                p[r * 100] = fmaf(acc2[ct][r], 0.0009765625f, acc1[ct][r]);
        }
    }
#undef ISSUE_A
#undef LOADSEC
#undef SEC_SYNC
#undef BODY
#undef SECTION
}

// ---------------- fused scan1 + gemm2 + scan2 — r15/r16 version verbatim ----------------
__global__ __launch_bounds__(576) void fused_scan3(const float* __restrict__ z1p,
                                                   const float* __restrict__ W2,
                                                   float* __restrict__ out) {
    __shared__ float fsm[32768];
    const int tid = threadIdx.x;
    const int b   = blockIdx.x;
    const float dt = FHN_DT;

    float V = 0.f, S = 0.f;
    const float* zb = z1p + (long)b * 2048 * 100 + tid;   // scan1 lanes only
    float z0[16], z1r[16], z2r[16], z3r[16];
    if (tid < 100) {
#pragma unroll
        for (int u = 0; u < 16; ++u) {
            z0[u]  = zb[u * 100];
            z1r[u] = zb[(16 + u) * 100];
            z2r[u] = zb[(32 + u) * 100];
            z3r[u] = zb[(48 + u) * 100];
        }
    }

    const int tg = tid - 128;                             // gemm2 threads: 0..383
    int pp = (tg >> 7) & 3;
    pp = __builtin_amdgcn_readfirstlane(pp);
    const int r  = tg & 127;
    const int mb = (pp == 0) ? 0 : (pp == 1 ? 4 : 7);
    const int mc = (pp == 0) ? 4 : 3;
    const int m2 = tid - 512;                             // scan2 lane id 0..9

    for (int i = 0; i <= 18; ++i) {
        if (tid < 128) {
            bool a1 = (tid < 100) && (i < 16);
            if (a1) {
#pragma unroll
                for (int sub = 0; sub < 8; ++sub) {
                    float zt[16];
                    int tn = (i * 8 + sub + 4) * 16;
                    if (tn < 2048) {
#pragma unroll
                        for (int u = 0; u < 16; ++u) zt[u] = zb[(tn + u) * 100];
                    }
                    const int cw = i & 1;
#pragma unroll
                    for (int u = 0; u < 16; ++u) {
                        int tl = sub * 16 + u;
                        fsm[cw * 14848 + tl * 116 + tid] = V;
                        float z  = z0[u];
                        float V3 = V * V * V;
                        float Vn = fmaf(1.f + dt, V,
                                    fmaf(-dt / 3.f, V3, fmaf(-dt, S, dt * z)));
                        float Sn = fmaf(dt * 0.08f, V + 0.7f - 0.8f * S, S);
                        V = Vn; S = Sn;
                    }
#pragma unroll
                    for (int u = 0; u < 16; ++u) {
                        z0[u] = z1r[u]; z1r[u] = z2r[u]; z2r[u] = z3r[u]; z3r[u] = zt[u];
                    }
                }
            }
        } else if (tid < 512) {
            if (i >= 1 && i <= 16) {
                const int pb = (i - 1) & 1;
                float acc[4] = {0.f, 0.f, 0.f, 0.f};
                for (int kq = 0; kq < 25; ++kq) {
                    float4 v = *(const float4*)&fsm[pb * 14848 + r * 116 + kq * 4];
#pragma unroll
                    for (int j = 0; j < 4; ++j) {
                        if (j < mc) {
                            const float* wp = W2 + (mb + j) * 100 + kq * 4;  // uniform -> s_load
                            acc[j] = fmaf(v.x, wp[0], acc[j]);
                            acc[j] = fmaf(v.y, wp[1], acc[j]);
                            acc[j] = fmaf(v.z, wp[2], acc[j]);
                            acc[j] = fmaf(v.w, wp[3], acc[j]);
                        }
                    }
                }
#pragma unroll
                for (int j = 0; j < 4; ++j)
                    if (j < mc) fsm[29696 + pb * 1536 + r * 12 + mb + j] = 0.5f * acc[j];
            }
            if (i >= 3) {
                const int pb = (i - 1) & 1;
                float* dst = out + ((long)b * 2048 + (long)(i - 3) * 128 + r) * 10;
#pragma unroll
                for (int j = 0; j < 4; ++j)
                    if (j < mc) dst[mb + j] = fsm[pb * 14848 + r * 116 + 100 + mb + j];
            }
        } else {
            bool a2 = (m2 < 10) && (i >= 2) && (i < 18);
            if (a2) {
                const int cw = i & 1;
#pragma unroll
                for (int sub = 0; sub < 8; ++sub) {
                    float z0s[16];
#pragma unroll
                    for (int u = 0; u < 16; ++u)
                        z0s[u] = fsm[29696 + cw * 1536 + (sub * 16 + u) * 12 + m2];
#pragma unroll
                    for (int u = 0; u < 16; ++u) {
                        int tl = sub * 16 + u;
                        fsm[cw * 14848 + tl * 116 + 100 + m2] = V;
                        float z  = z0s[u];
                        float V3 = V * V * V;
                        float Vn = fmaf(1.f + dt, V,
                                    fmaf(-dt / 3.f, V3, fmaf(-dt, S, dt * z)));
                        float Sn = fmaf(dt * 0.08f, V + 0.7f - 0.8f * S, S);
                        V = Vn; S = Sn;
                    }
                }
            }
        }
        sync_lds();
    }
}

extern "C" void kernel_launch(void* const* d_in, const int* in_sizes, int n_in,
                              void* d_out, int out_size, void* d_ws, size_t ws_size,
                              hipStream_t stream) {
    const float* batch = (const float*)d_in[0];   // 64*2048*784
    const float* W1    = (const float*)d_in[1];   // 100*784
    const float* W2    = (const float*)d_in[2];   // 10*100
    float* out = (float*)d_out;                   // 64*2048*10

    char* base = (char*)d_ws;
    unsigned short* Wg = (unsigned short*)base;   // 358400 B
    float* z1p = (float*)(base + 358400);         // 131072*100 f32

    prep_w16<<<700, 256, 0, stream>>>(W1, Wg);
    gemm1_x<<<1024, 512, 0, stream>>>(batch, Wg, z1p);
    fused_scan3<<<64, 576, 0, stream>>>(z1p, W2, out);
}

// Round 18
// 201.966 us; speedup vs baseline: 1.0166x; 1.0166x over previous
//
#include <hip/hip_runtime.h>
#include <hip/hip_bf16.h>

// B=64, T=2048, D=784, N1=100, N2=10, dt=0.04
// Pipeline:
//   prep_w16 : W1 -> fp16 2-way split (h, r*1024) in FRAGMENT ORDER (r16 verbatim)
//   gemm1_w4 : r16's barrier-free persistent-W kernel with 4-DEEP A register
//              flight (afpA..D; issue A(KT+4) into the buffer just consumed)
//              -> ~3 tiles (96 KB/CU) outstanding to cover loaded-HBM latency.
//   fused_scan4: r15/r16 fused_scan3 with scan1's z-prefetch converted to
//              static modular buffers (no register shifting; bit-identical).
//
// ws: Wg 358400 B | z1p 131072*100 f32 (52.4 MB)

#define FHN_DT 0.04f

typedef _Float16 f16x8 __attribute__((ext_vector_type(8)));
typedef __attribute__((ext_vector_type(4))) float f32x4;

__device__ __forceinline__ void gl16(const void* g, void* l) {
    __builtin_amdgcn_global_load_lds(
        (const __attribute__((address_space(1))) unsigned int*)g,
        (__attribute__((address_space(3))) unsigned int*)l, 16, 0, 0);
}

__device__ __forceinline__ void sync_lds() {
    asm volatile("s_waitcnt lgkmcnt(0)" ::: "memory");
    __builtin_amdgcn_s_barrier();
    asm volatile("" ::: "memory");
}

// ---------------- prep: W1 (100x784) -> fragment-order fp16 split image (r16 verbatim) ----------------
__global__ void prep_w16(const float* __restrict__ W1, unsigned short* __restrict__ Wg) {
    int idx = blockIdx.x * 256 + threadIdx.x;
    if (idx >= 179200) return;
    int kt   = idx / 7168;
    int rem  = idx % 7168;
    int f    = rem >> 9;
    int r2   = rem & 511;
    int l    = r2 >> 3;
    int e    = r2 & 7;
    int term = f / 7, ct = f % 7;
    int n = ct * 16 + (l & 15);
    int k = kt * 32 + (l >> 4) * 8 + e;
    float v = (n < 100 && k < 784) ? W1[n * 784 + k] : 0.0f;
    _Float16 h = (_Float16)v;
    unsigned short o;
    if (term == 0) o = __builtin_bit_cast(unsigned short, h);
    else           o = __builtin_bit_cast(unsigned short, (_Float16)((v - (float)h) * 1024.0f));
    Wg[idx] = o;
}

// ---------------- GEMM1: barrier-free, W persistent in LDS (3 sections), 4-deep A flight ----------------
__global__ __launch_bounds__(512, 1) void gemm1_w4(const float* __restrict__ A,
                                                   const unsigned short* __restrict__ Wg,
                                                   float* __restrict__ z1p) {
    __shared__ __align__(16) char smem[129024];    // 9 tiles x 14336 B (max section)
    const int tid  = threadIdx.x;                  // 0..511
    const int w    = tid >> 6;                     // 0..7
    const int lane = tid & 63;
    const int ln   = lane & 15;
    const int kg   = lane >> 4;                    // k-slice = kg*8
    const long row0 = (long)blockIdx.x * 256;

    const float* arow0 = A + (row0 + w * 32 + ln) * 784 + kg * 8;
    const float* arow1 = arow0 + (size_t)16 * 784;

    f32x4 acc1[2][7] = {};
    f32x4 acc2[2][7] = {};
    float afpA[16], afpB[16], afpC[16], afpD[16];  // [0..7] row0, [8..15] row1

#define ISSUE_A(T, AF) {                                                        \
        if ((T) == 24 && kg >= 2) {                                             \
            *(float4*)&AF[0]  = make_float4(0.f, 0.f, 0.f, 0.f);                \
            *(float4*)&AF[4]  = make_float4(0.f, 0.f, 0.f, 0.f);                \
            *(float4*)&AF[8]  = make_float4(0.f, 0.f, 0.f, 0.f);                \
            *(float4*)&AF[12] = make_float4(0.f, 0.f, 0.f, 0.f);                \
        } else {                                                                \
            *(float4*)&AF[0]  = *(const float4*)(arow0 + (T) * 32);             \
            *(float4*)&AF[4]  = *(const float4*)(arow0 + (T) * 32 + 4);         \
            *(float4*)&AF[8]  = *(const float4*)(arow1 + (T) * 32);             \
            *(float4*)&AF[12] = *(const float4*)(arow1 + (T) * 32 + 4);         \
        } }

    // bulk W-section copy: linear, wave-uniform base + lane*16 (DMA-native)
#define LOADSEC(TS, NB) {                                                       \
        const char* src_ = (const char*)Wg + (size_t)(TS) * 14336;              \
        _Pragma("unroll 1")                                                     \
        for (int c_ = 0; c_ < (NB) / 8192; ++c_)                                \
            gl16(src_ + c_ * 8192 + tid * 16, smem + c_ * 8192 + tid * 16);     \
        if (((NB) & 8191) != 0 && tid * 16 < ((NB) & 8191))                     \
            gl16(src_ + ((NB) / 8192) * 8192 + tid * 16,                        \
                 smem + ((NB) / 8192) * 8192 + tid * 16);                       \
    }

#define SEC_SYNC() {                                                            \
        asm volatile("s_waitcnt vmcnt(0)" ::: "memory");                        \
        __builtin_amdgcn_s_barrier();                                           \
        asm volatile("" ::: "memory");                                          \
    }

    // barrier-free body: wait own A (compiler vmcnt), split, re-issue buffer, MFMA
#define BODY(KT, AF, TS) {                                                      \
        f16x8 ah0, al0, ah1, al1;                                               \
        _Pragma("unroll")                                                       \
        for (int e_ = 0; e_ < 8; ++e_) {                                        \
            float a0_ = AF[e_], a1_ = AF[8 + e_];                               \
            _Float16 h0_ = (_Float16)a0_, h1_ = (_Float16)a1_;                  \
            ah0[e_] = h0_; ah1[e_] = h1_;                                       \
            al0[e_] = (_Float16)((a0_ - (float)h0_) * 1024.0f);                 \
            al1[e_] = (_Float16)((a1_ - (float)h1_) * 1024.0f);                 \
        }                                                                       \
        if ((KT) < 21) ISSUE_A((KT) + 4, AF);                                   \
        const char* cb_ = smem + ((KT) - (TS)) * 14336 + lane * 16;             \
        _Pragma("unroll")                                                       \
        for (int ct_ = 0; ct_ < 7; ++ct_) {                                     \
            f16x8 bh = *(const f16x8*)(cb_ + ct_ * 1024);                       \
            f16x8 bl = *(const f16x8*)(cb_ + 7168 + ct_ * 1024);                \
            acc1[0][ct_] = __builtin_amdgcn_mfma_f32_16x16x32_f16(ah0, bh, acc1[0][ct_], 0, 0, 0); \
            acc2[0][ct_] = __builtin_amdgcn_mfma_f32_16x16x32_f16(ah0, bl, acc2[0][ct_], 0, 0, 0); \
            acc2[0][ct_] = __builtin_amdgcn_mfma_f32_16x16x32_f16(al0, bh, acc2[0][ct_], 0, 0, 0); \
            acc1[1][ct_] = __builtin_amdgcn_mfma_f32_16x16x32_f16(ah1, bh, acc1[1][ct_], 0, 0, 0); \
            acc2[1][ct_] = __builtin_amdgcn_mfma_f32_16x16x32_f16(ah1, bl, acc2[1][ct_], 0, 0, 0); \
            acc2[1][ct_] = __builtin_amdgcn_mfma_f32_16x16x32_f16(al1, bh, acc2[1][ct_], 0, 0, 0); \
        } }

    // prologue: A tiles 0..3 in flight (buffer = tile % 4)
    ISSUE_A(0, afpA);
    ISSUE_A(1, afpB);
    ISSUE_A(2, afpC);
    ISSUE_A(3, afpD);

    // ---- section 0: tiles 0..8 ----
    LOADSEC(0, 129024);
    SEC_SYNC();
    BODY(0, afpA, 0); BODY(1, afpB, 0); BODY(2, afpC, 0); BODY(3, afpD, 0);
    BODY(4, afpA, 0); BODY(5, afpB, 0); BODY(6, afpC, 0); BODY(7, afpD, 0);
    BODY(8, afpA, 0);

    // ---- section 1: tiles 9..16 ----
    asm volatile("" ::: "memory");
    __builtin_amdgcn_s_barrier();      // all waves done reading section 0
    asm volatile("" ::: "memory");
    LOADSEC(9, 114688);
    SEC_SYNC();
    BODY(9,  afpB, 9); BODY(10, afpC, 9); BODY(11, afpD, 9); BODY(12, afpA, 9);
    BODY(13, afpB, 9); BODY(14, afpC, 9); BODY(15, afpD, 9); BODY(16, afpA, 9);

    // ---- section 2: tiles 17..24 ----
    asm volatile("" ::: "memory");
    __builtin_amdgcn_s_barrier();
    asm volatile("" ::: "memory");
    LOADSEC(17, 114688);
    SEC_SYNC();
    BODY(17, afpB, 17); BODY(18, afpC, 17); BODY(19, afpD, 17); BODY(20, afpA, 17);
    BODY(21, afpB, 17); BODY(22, afpC, 17); BODY(23, afpD, 17); BODY(24, afpA, 17);

    // ---- epilogue: C/D map col = lane&15, row = kg*4 + r ; z = acc1 + acc2/1024 ----
#pragma unroll
    for (int ct = 0; ct < 7; ++ct) {
        int n = ct * 16 + ln;
        if (n < 100) {
#pragma unroll
            for (int rt = 0; rt < 2; ++rt) {
                long rg = row0 + w * 32 + rt * 16 + kg * 4;
                float* p = z1p + rg * 100 + n;
#pragma unroll
                for (int r = 0; r < 4; ++r)
                    p[r * 100] = fmaf(acc2[rt][ct][r], 0.0009765625f, acc1[rt][ct][r]);
            }
        }
    }
#undef ISSUE_A
#undef LOADSEC
#undef SEC_SYNC
#undef BODY
}

// ---------------- fused scan1 + gemm2 + scan2 — static z-buffer rotation ----------------
// 64 blocks x 576. tid 0..99 scan1; 128..511 gemm2+copyout; 512..521 scan2.
// scan1: consume zbuf[g%4] for group g = i*8+sub, then reload same buffer with
// group g+4 (all indices compile-time after unroll; loads/arithmetic identical
// to r15/r16 -> bit-exact output, just no register shifting).
__global__ __launch_bounds__(576) void fused_scan4(const float* __restrict__ z1p,
                                                   const float* __restrict__ W2,
                                                   float* __restrict__ out) {
    __shared__ float fsm[32768];
    const int tid = threadIdx.x;
    const int b   = blockIdx.x;
    const float dt = FHN_DT;

    float V = 0.f, S = 0.f;
    const float* zb = z1p + (long)b * 2048 * 100 + tid;   // scan1 lanes only
    float zb0[16], zb1[16], zb2[16], zb3[16];
    if (tid < 100) {
#pragma unroll
        for (int u = 0; u < 16; ++u) {
            zb0[u] = zb[u * 100];
            zb1[u] = zb[(16 + u) * 100];
            zb2[u] = zb[(32 + u) * 100];
            zb3[u] = zb[(48 + u) * 100];
        }
    }

    const int tg = tid - 128;                             // gemm2 threads: 0..383
    int pp = (tg >> 7) & 3;
    pp = __builtin_amdgcn_readfirstlane(pp);
    const int r  = tg & 127;
    const int mb = (pp == 0) ? 0 : (pp == 1 ? 4 : 7);
    const int mc = (pp == 0) ? 4 : 3;
    const int m2 = tid - 512;                             // scan2 lane id 0..9

    for (int i = 0; i <= 18; ++i) {
        if (tid < 128) {
            bool a1 = (tid < 100) && (i < 16);
            if (a1) {
                const int cw = i & 1;
#define S1STEP(SUB, ZC) {                                                       \
                _Pragma("unroll")                                               \
                for (int u = 0; u < 16; ++u) {                                  \
                    int tl = (SUB) * 16 + u;                                    \
                    fsm[cw * 14848 + tl * 116 + tid] = V;                       \
                    float z  = ZC[u];                                           \
                    float V3 = V * V * V;                                       \
                    float Vn = fmaf(1.f + dt, V,                                \
                                fmaf(-dt / 3.f, V3, fmaf(-dt, S, dt * z)));     \
                    float Sn = fmaf(dt * 0.08f, V + 0.7f - 0.8f * S, S);        \
                    V = Vn; S = Sn;                                             \
                }                                                               \
                {                                                               \
                    int tn = (i * 8 + (SUB) + 4) * 16;                          \
                    if (tn < 2048) {                                            \
                        _Pragma("unroll")                                       \
                        for (int u = 0; u < 16; ++u) ZC[u] = zb[(tn + u) * 100];\
                    }                                                           \
                } }
                S1STEP(0, zb0) S1STEP(1, zb1) S1STEP(2, zb2) S1STEP(3, zb3)
                S1STEP(4, zb0) S1STEP(5, zb1) S1STEP(6, zb2) S1STEP(7, zb3)
#undef S1STEP
            }
        } else if (tid < 512) {
            if (i >= 1 && i <= 16) {
                const int pb = (i - 1) & 1;
                float acc[4] = {0.f, 0.f, 0.f, 0.f};
                for (int kq = 0; kq < 25; ++kq) {
                    float4 v = *(const float4*)&fsm[pb * 14848 + r * 116 + kq * 4];
#pragma unroll
                    for (int j = 0; j < 4; ++j) {
                        if (j < mc) {
                            const float* wp = W2 + (mb + j) * 100 + kq * 4;  // uniform -> s_load
                            acc[j] = fmaf(v.x, wp[0], acc[j]);
                            acc[j] = fmaf(v.y, wp[1], acc[j]);
                            acc[j] = fmaf(v.z, wp[2], acc[j]);
                            acc[j] = fmaf(v.w, wp[3], acc[j]);
                        }
                    }
                }
#pragma unroll
                for (int j = 0; j < 4; ++j)
                    if (j < mc) fsm[29696 + pb * 1536 + r * 12 + mb + j] = 0.5f * acc[j];
            }
            if (i >= 3) {
                const int pb = (i - 1) & 1;
                float* dst = out + ((long)b * 2048 + (long)(i - 3) * 128 + r) * 10;
#pragma unroll
                for (int j = 0; j < 4; ++j)
                    if (j < mc) dst[mb + j] = fsm[pb * 14848 + r * 116 + 100 + mb + j];
            }
        } else {
            bool a2 = (m2 < 10) && (i >= 2) && (i < 18);
            if (a2) {
                const int cw = i & 1;
#pragma unroll
                for (int sub = 0; sub < 8; ++sub) {
                    float z0s[16];
#pragma unroll
                    for (int u = 0; u < 16; ++u)
                        z0s[u] = fsm[29696 + cw * 1536 + (sub * 16 + u) * 12 + m2];
#pragma unroll
                    for (int u = 0; u < 16; ++u) {
                        int tl = sub * 16 + u;
                        fsm[cw * 14848 + tl * 116 + 100 + m2] = V;
                        float z  = z0s[u];
                        float V3 = V * V * V;
                        float Vn = fmaf(1.f + dt, V,
                                    fmaf(-dt / 3.f, V3, fmaf(-dt, S, dt * z)));
                        float Sn = fmaf(dt * 0.08f, V + 0.7f - 0.8f * S, S);
                        V = Vn; S = Sn;
                    }
                }
            }
        }
        sync_lds();
    }
}

extern "C" void kernel_launch(void* const* d_in, const int* in_sizes, int n_in,
                              void* d_out, int out_size, void* d_ws, size_t ws_size,
                              hipStream_t stream) {
    const float* batch = (const float*)d_in[0];   // 64*2048*784
    const float* W1    = (const float*)d_in[1];   // 100*784
    const float* W2    = (const float*)d_in[2];   // 10*100
    float* out = (float*)d_out;                   // 64*2048*10

    char* base = (char*)d_ws;
    unsigned short* Wg = (unsigned short*)base;   // 358400 B
    float* z1p = (float*)(base + 358400);         // 131072*100 f32

    prep_w16<<<700, 256, 0, stream>>>(W1, Wg);
    gemm1_w4<<<512, 512, 0, stream>>>(batch, Wg, z1p);
    fused_scan4<<<64, 576, 0, stream>>>(z1p, W2, out);
}